// Round 1
// baseline (1216.769 us; speedup 1.0000x reference)
//
#include <hip/hip_runtime.h>
#include <math.h>

// ExactContinuousSBM: reverse VP-SDE sampling of a Gaussian mixture.
// Round 4: occupancy restructure. 512-thread blocks (8 waves) x 512 blocks
// -> 16 waves/CU (4/SIMD) instead of 8 (2/SIMD). k-split 8-way across waves;
// cross-wave merge is NO LONGER replicated: each wave merges only its own
// 2x32 (b,d) slice scalar-per-lane and publishes x through s_x (2nd barrier).
// gen table writes made bank-linear; gen uses product+1 log instead of 4 logs;
// noise is a 1-VGPR scalar prefetch (merge role). s_n/s_ml single-buffered.

namespace {

constexpr int BD   = 8192;
constexpr int DIMN = 32;
constexpr int KM   = 64;
constexpr int NST  = 255;
constexpr float TMINc = 1e-4f, TMAXc = 1.0f;
constexpr float BMIN = 0.1f,  BMAX = 20.0f;
constexpr float L2E = 1.4426950408889634f;   // log2(e)
constexpr float LN2 = 0.6931471805599453f;

// DPP butterfly add over 8 consecutive lanes:
// 0xB1 = quad_perm xor1, 0x4E = quad_perm xor2, 0x141 = row_half_mirror.
template <int CTRL>
__device__ __forceinline__ float dpp_addf(float v) {
  int o = __builtin_amdgcn_update_dpp(0, __float_as_int(v), CTRL, 0xf, 0xf, true);
  return v + __int_as_float(o);
}
__device__ __forceinline__ float dred8(float v) {
  v = dpp_addf<0xB1>(v);
  v = dpp_addf<0x4E>(v);
  v = dpp_addf<0x141>(v);
  return v;
}

__global__ __launch_bounds__(512, 4) void sbm_kernel(
    const float* __restrict__ xin,    // [8192,32]
    const float* __restrict__ cen_g,  // [64,32]
    const float* __restrict__ std_g,  // [64,32]
    const float* __restrict__ w_g,    // [64]
    const float* __restrict__ noi,    // [255,8192,32]
    float* __restrict__ out)          // [8192,32]
{
  __shared__ __align__(16) float  s_iv[2][KM][DIMN];  // log2e / v
  __shared__ __align__(16) float  s_a [2][KM][DIMN];  // m * log2e / v
  __shared__ __align__(16) float  s_c [2][KM];        // log2-domain const
  __shared__ __align__(16) float4 s_n [8][16][8];     // [wave][b][dchunk] numerators
  __shared__ __align__(16) float2 s_ml[8][16];        // [wave][b] (M, L)
  __shared__ __align__(16) float  s_x [16][DIMN];     // block's x state

  const int tid  = threadIdx.x;
  const int w    = tid >> 6;        // wave 0..7 -> k range
  const int lane = tid & 63;
  const int dc   = lane & 7;        // d-chunk (4 dims)
  const int slot = lane >> 3;       // b slot 0..7 (b0=slot, b1=slot+8)
  const int d0   = dc * 4;
  const int k0   = w * 8;
  const int bbase = blockIdx.x * 16;

  // gen role: thread -> (k = tid>>3, 4 dims at (tid&7)*4). Per-wave table
  // stores are a linear 1024B region -> no bank conflicts.
  const int gk = tid >> 3;
  const int gd = (tid & 7) * 4;
  float cen[4], s2[4];
  {
    const float4 c4 = *reinterpret_cast<const float4*>(cen_g + gk * DIMN + gd);
    const float4 s4 = *reinterpret_cast<const float4*>(std_g + gk * DIMN + gd);
    cen[0]=c4.x; cen[1]=c4.y; cen[2]=c4.z; cen[3]=c4.w;
    s2[0]=s4.x*s4.x; s2[1]=s4.y*s4.y; s2[2]=s4.z*s4.z; s2[3]=s4.w*s4.w;
  }
  const float lw2 = __builtin_amdgcn_logf(w_g[gk]);   // log2(w)

  // merge role: wave w owns local b's {2w, 2w+1}; lane -> (mb, md) scalar.
  const int mb = (w << 1) + (lane >> 5);
  const int md = lane & 31;

  auto gen = [&](int buf, int jj) {
    const float t  = fmaf((float)(255 - jj) * (1.0f / 255.0f), (TMAXc - TMINc), TMINc);
    const float Bt = fmaf(0.5f * (BMAX - BMIN), t * t, BMIN * t);
    const float eB  = __builtin_amdgcn_exp2f(-Bt * L2E);
    const float om  = 1.0f - eB;
    const float smB = __builtin_amdgcn_sqrtf(eB);
    float cq = 0.0f, pv = 1.0f;
    float ivv[4], av[4];
#pragma unroll
    for (int i = 0; i < 4; ++i) {
      const float v  = fmaf(eB, s2[i], om);
      const float iv = L2E * __builtin_amdgcn_rcpf(v);
      const float m  = smB * cen[i];
      const float A  = m * iv;
      ivv[i] = iv; av[i] = A;
      cq = fmaf(m, A, cq);                 // log2e * m^2/v
      pv *= v;                             // product -> one log2
    }
    *reinterpret_cast<float4*>(&s_iv[buf][gk][gd]) = make_float4(ivv[0], ivv[1], ivv[2], ivv[3]);
    *reinterpret_cast<float4*>(&s_a [buf][gk][gd]) = make_float4(av[0], av[1], av[2], av[3]);
    const float q1 = dred8(cq);                               // sum over 8 lanes
    const float q2 = dred8(__builtin_amdgcn_logf(pv));        // sum of log2 v
    if ((tid & 7) == 0)
      s_c[buf][gk] = fmaf(-16.0f, q2, fmaf(-0.5f, q1, lw2));
  };

  float x_m = xin[(size_t)(bbase + mb) * DIMN + md];
  s_x[mb][md] = x_m;
  gen(0, 0);
  __syncthreads();

#pragma unroll 1
  for (int j = 0; j < NST; ++j) {
    const int buf = j & 1;

    // merge-role noise prefetch (scalar; consumed after barrier A)
    const float z_m = noi[((size_t)j * BD + (bbase + mb)) * (size_t)DIMN + md];

    // compute-role x (published by merge of previous step through s_x)
    float x0[4], x1[4];
    {
      const float4 a = *reinterpret_cast<const float4*>(&s_x[slot][d0]);
      const float4 b = *reinterpret_cast<const float4*>(&s_x[slot + 8][d0]);
      x0[0]=a.x; x0[1]=a.y; x0[2]=a.z; x0[3]=a.w;
      x1[0]=b.x; x1[1]=b.y; x1[2]=b.z; x1[3]=b.w;
    }

    if (j + 1 < NST) gen(buf ^ 1, j + 1);   // tables for next step (other buf)

    const float t  = fmaf((float)(255 - j) * (1.0f / 255.0f), (TMAXc - TMINc), TMINc);
    const float tn = fmaf((float)(254 - j) * (1.0f / 255.0f), (TMAXc - TMINc), TMINc);
    const float dt = tn - t;                 // negative
    const float bt = fmaf(BMAX - BMIN, t, BMIN);

    float h0[4], h1[4];
#pragma unroll
    for (int i = 0; i < 4; ++i) { h0[i] = -0.5f * x0[i] * x0[i]; h1[i] = -0.5f * x1[i] * x1[i]; }

    float M0 = 0.0f, M1 = 0.0f;
    float L0 = 0.0f, L1 = 0.0f;
    float SIV0[4] = {0,0,0,0}, SA0[4] = {0,0,0,0};
    float SIV1[4] = {0,0,0,0}, SA1[4] = {0,0,0,0};

#pragma unroll
    for (int sc = 0; sc < 2; ++sc) {
      const int kc = k0 + sc * 4;
      const float4 ccv = *reinterpret_cast<const float4*>(&s_c[buf][kc]);
      const float cc[4] = {ccv.x, ccv.y, ccv.z, ccv.w};

      float4 tiv[4], ta[4];
      float p0[4], p1[4];
      float cm0 = -__builtin_inff(), cm1 = -__builtin_inff();
#pragma unroll
      for (int kk = 0; kk < 4; ++kk) {
        tiv[kk] = *reinterpret_cast<const float4*>(&s_iv[buf][kc + kk][d0]);
        ta[kk]  = *reinterpret_cast<const float4*>(&s_a [buf][kc + kk][d0]);
        float pa = h0[0] * tiv[kk].x;
        pa = fmaf(x0[0], ta[kk].x, pa);
        pa = fmaf(h0[1], tiv[kk].y, pa);
        pa = fmaf(x0[1], ta[kk].y, pa);
        pa = fmaf(h0[2], tiv[kk].z, pa);
        pa = fmaf(x0[2], ta[kk].z, pa);
        pa = fmaf(h0[3], tiv[kk].w, pa);
        pa = fmaf(x0[3], ta[kk].w, pa);
        float pb = h1[0] * tiv[kk].x;
        pb = fmaf(x1[0], ta[kk].x, pb);
        pb = fmaf(h1[1], tiv[kk].y, pb);
        pb = fmaf(x1[1], ta[kk].y, pb);
        pb = fmaf(h1[2], tiv[kk].z, pb);
        pb = fmaf(x1[2], ta[kk].z, pb);
        pb = fmaf(h1[3], tiv[kk].w, pb);
        pb = fmaf(x1[3], ta[kk].w, pb);
        pa = dred8(pa) + cc[kk];
        pb = dred8(pb) + cc[kk];
        p0[kk] = pa; p1[kk] = pb;
        cm0 = fmaxf(cm0, pa); cm1 = fmaxf(cm1, pb);
      }
      if (sc == 0) {           // first sub-chunk: no rescale needed
        M0 = cm0; M1 = cm1;
      } else {                 // second sub-chunk: one rescale
        const float nM0 = fmaxf(M0, cm0), nM1 = fmaxf(M1, cm1);
        const float al0 = __builtin_amdgcn_exp2f(M0 - nM0);
        const float al1 = __builtin_amdgcn_exp2f(M1 - nM1);
        M0 = nM0; M1 = nM1;
        L0 *= al0; L1 *= al1;
#pragma unroll
        for (int i = 0; i < 4; ++i) {
          SIV0[i] *= al0; SA0[i] *= al0;
          SIV1[i] *= al1; SA1[i] *= al1;
        }
      }
#pragma unroll
      for (int kk = 0; kk < 4; ++kk) {
        const float e0 = __builtin_amdgcn_exp2f(p0[kk] - M0);
        const float e1 = __builtin_amdgcn_exp2f(p1[kk] - M1);
        L0 += e0; L1 += e1;
        SIV0[0] = fmaf(e0, tiv[kk].x, SIV0[0]);
        SIV0[1] = fmaf(e0, tiv[kk].y, SIV0[1]);
        SIV0[2] = fmaf(e0, tiv[kk].z, SIV0[2]);
        SIV0[3] = fmaf(e0, tiv[kk].w, SIV0[3]);
        SA0[0]  = fmaf(e0, ta[kk].x, SA0[0]);
        SA0[1]  = fmaf(e0, ta[kk].y, SA0[1]);
        SA0[2]  = fmaf(e0, ta[kk].z, SA0[2]);
        SA0[3]  = fmaf(e0, ta[kk].w, SA0[3]);
        SIV1[0] = fmaf(e1, tiv[kk].x, SIV1[0]);
        SIV1[1] = fmaf(e1, tiv[kk].y, SIV1[1]);
        SIV1[2] = fmaf(e1, tiv[kk].z, SIV1[2]);
        SIV1[3] = fmaf(e1, tiv[kk].w, SIV1[3]);
        SA1[0]  = fmaf(e1, ta[kk].x, SA1[0]);
        SA1[1]  = fmaf(e1, ta[kk].y, SA1[1]);
        SA1[2]  = fmaf(e1, ta[kk].z, SA1[2]);
        SA1[3]  = fmaf(e1, ta[kk].w, SA1[3]);
      }
    }

    // per-wave numerators n = SA - x*SIV (un-scaled; scaled at merge).
    // store is a linear region per wave -> bank-conflict-free.
    {
      const float4 n0 = make_float4(fmaf(-x0[0], SIV0[0], SA0[0]),
                                    fmaf(-x0[1], SIV0[1], SA0[1]),
                                    fmaf(-x0[2], SIV0[2], SA0[2]),
                                    fmaf(-x0[3], SIV0[3], SA0[3]));
      const float4 n1 = make_float4(fmaf(-x1[0], SIV1[0], SA1[0]),
                                    fmaf(-x1[1], SIV1[1], SA1[1]),
                                    fmaf(-x1[2], SIV1[2], SA1[2]),
                                    fmaf(-x1[3], SIV1[3], SA1[3]));
      s_n[w][slot][dc]     = n0;
      s_n[w][slot + 8][dc] = n1;
      if (dc == 0) {
        s_ml[w][slot]     = make_float2(M0, L0);
        s_ml[w][slot + 8] = make_float2(M1, L1);
      }
    }
    __syncthreads();   // A: n/ml handoff complete

    // ---- de-replicated merge: this wave merges only (mb, md), scalar ----
    {
      const float cA  = fmaf(-0.5f * bt, dt, 1.0f);
      const float cb0 = (-bt * dt) * LN2;
      const float sq  = __builtin_amdgcn_sqrtf(bt) * __builtin_amdgcn_sqrtf(-dt);

      float Mv[8], Lv[8];
#pragma unroll
      for (int q = 0; q < 8; ++q) {
        const float2 ml = s_ml[q][mb];   // broadcast reads
        Mv[q] = ml.x; Lv[q] = ml.y;
      }
      const float Gm = fmaxf(fmaxf(fmaxf(Mv[0], Mv[1]), fmaxf(Mv[2], Mv[3])),
                             fmaxf(fmaxf(Mv[4], Mv[5]), fmaxf(Mv[6], Mv[7])));
      float Lt = 0.0f, nu = 0.0f;
#pragma unroll
      for (int q = 0; q < 8; ++q) {
        const float s = __builtin_amdgcn_exp2f(Mv[q] - Gm);
        Lt = fmaf(s, Lv[q], Lt);
        // scalar n read: 64 consecutive words -> 2 lanes/bank (free)
        nu = fmaf(s, reinterpret_cast<const float*>(&s_n[q][mb][0])[md], nu);
      }
      const float cb2 = cb0 * __builtin_amdgcn_rcpf(Lt);
      const float xn  = fmaf(cb2, nu, fmaf(cA, x_m, sq * z_m));
      s_x[mb][md] = xn;
      if (j == NST - 1) out[(size_t)(bbase + mb) * DIMN + md] = xn;
      x_m = xn;
    }
    __syncthreads();   // B: x published for next step's compute reads
  }
}

}  // namespace

extern "C" void kernel_launch(void* const* d_in, const int* in_sizes, int n_in,
                              void* d_out, int out_size, void* d_ws, size_t ws_size,
                              hipStream_t stream) {
  const float* x_init  = (const float*)d_in[0];
  const float* centers = (const float*)d_in[1];
  const float* stds    = (const float*)d_in[2];
  const float* weights = (const float*)d_in[3];
  const float* noise   = (const float*)d_in[4];
  float* out = (float*)d_out;

  sbm_kernel<<<dim3(512), dim3(512), 0, stream>>>(x_init, centers, stds, weights,
                                                  noise, out);
}

// Round 2
// 1004.166 us; speedup vs baseline: 1.2117x; 1.2117x over previous
//
#include <hip/hip_runtime.h>
#include <math.h>

// ExactContinuousSBM: reverse VP-SDE sampling of a Gaussian mixture.
// Round 5: MFMA restructure. Both inner products (P = logits matmul,
// O = responsibility-weighted accumulation) moved to v_mfma_f32_16x16x32_bf16
// with bf16-hi/lo split operands (4-term products ~= fp32 precision).
// The log-normalizer c_k is folded into the P-matmul via two "ones x G"
// chunks (G = -0.5*m*a - 16*log2 v (+log2 w at d==0), split hi/lo).
// Softmax runs on the MFMA D-fragment layout (col=lane&15, row=hi*4+reg,
// m89-verified): DPP butterfly over 16 k-cols + cross-wave merge in LDS.
// 256 thr (4 waves) x 512 blocks, 16 b/block, 2 blocks/CU (LDS ~57KB).

namespace {

constexpr int BD   = 8192;
constexpr int DIMN = 32;
constexpr int NST  = 255;
constexpr float TMINc = 1e-4f, TMAXc = 1.0f;
constexpr float BMIN = 0.1f,  BMAX = 20.0f;
constexpr float L2E = 1.4426950408889634f;   // log2(e)
constexpr float LN2 = 0.6931471805599453f;

typedef float f32x4  __attribute__((ext_vector_type(4)));
typedef short bf16x8 __attribute__((ext_vector_type(8)));
typedef int   i32x4  __attribute__((ext_vector_type(4)));

__device__ __forceinline__ bf16x8 frag4(unsigned w0, unsigned w1,
                                        unsigned w2, unsigned w3) {
  i32x4 t; t[0] = (int)w0; t[1] = (int)w1; t[2] = (int)w2; t[3] = (int)w3;
  return __builtin_bit_cast(bf16x8, t);
}

// fp32 -> (bf16 hi, bf16 lo) split; hi+lo ~= x to ~2^-17 relative.
__device__ __forceinline__ uint2 bsplit(float x) {
  unsigned u  = __float_as_uint(x);
  unsigned uh = (u + 0x8000u) & 0xFFFF0000u;
  float lf = x - __uint_as_float(uh);
  unsigned ul = (__float_as_uint(lf) + 0x8000u) >> 16;
  return make_uint2(uh >> 16, ul & 0xFFFFu);
}
__device__ __forceinline__ unsigned spack(float x) {   // hi | lo<<16
  uint2 s = bsplit(x);
  return s.x | (s.y << 16);
}

// DPP value-move (returns permuted lanes' value)
template <int CTRL>
__device__ __forceinline__ float dpp_mov(float v) {
  return __int_as_float(
      __builtin_amdgcn_update_dpp(0, __float_as_int(v), CTRL, 0xf, 0xf, true));
}
// Butterfly reductions over each 16-lane group:
// xor1 (quad_perm 0xB1), xor2 (0x4E), then half_mirror(0x141)/mirror(0x140)
// which act as xor4/xor8 once the smaller groups are uniform.
__device__ __forceinline__ float bfly_max16(float v) {
  v = fmaxf(v, dpp_mov<0xB1>(v));
  v = fmaxf(v, dpp_mov<0x4E>(v));
  v = fmaxf(v, dpp_mov<0x141>(v));
  v = fmaxf(v, dpp_mov<0x140>(v));
  return v;
}
__device__ __forceinline__ float bfly_add16(float v) {
  v += dpp_mov<0xB1>(v);
  v += dpp_mov<0x4E>(v);
  v += dpp_mov<0x141>(v);
  v += dpp_mov<0x140>(v);
  return v;
}

__global__ __launch_bounds__(256, 2) void sbm_kernel(
    const float* __restrict__ xin,    // [8192,32]
    const float* __restrict__ cen_g,  // [64,32]
    const float* __restrict__ std_g,  // [64,32]
    const float* __restrict__ w_g,    // [64]
    const float* __restrict__ noi,    // [255,8192,32]
    float* __restrict__ out)          // [8192,32]
{
  // P-matmul table frags: per (ntile, chunk q, lane): (IVh|IVl, Ah|Al)
  __shared__ __align__(16) uint2 s_pt[4][8][64];        // 16 KB
  // G frags (ones-chunks): per (ntile, g, lane): 4 words Gh|Gl
  __shared__ __align__(16) uint4 s_gt[4][2][64];        // 8 KB
  // O-matmul tables, [col][k] so (k0,k0+1) is a b64: col = 16*(d>>3)+2*(d&7)+s
  __shared__ __align__(16) unsigned s_ot[64][68];       // 17 KB
  // P-matmul data frags (shared by all waves): per (chunk q, lane) b128
  __shared__ __align__(16) uint4 s_df[8][64];           // 8 KB
  // E (unnormalized responsibilities), split-packed: [b][k]
  __shared__ __align__(16) unsigned s_E[16][68];        // 4.25 KB
  // x state
  __shared__ __align__(16) float s_x[16][33];           // 2.1 KB
  // softmax cross-wave partials
  __shared__ __align__(16) float s_pm[16][4];
  __shared__ __align__(16) float s_pl[16][4];

  const int tid  = threadIdx.x;
  const int w    = tid >> 6;        // wave 0..3 = ntile (k-tile / d-tile)
  const int lane = tid & 63;
  const int l15  = lane & 15;
  const int hi   = lane >> 4;
  const int bbase = blockIdx.x * 16;

  // ---- gen role: this thread owns k = w*16+l15, d = q*4+hi for q=0..7 ----
  const int kg = w * 16 + l15;
  float cenv[8], cen2v[8], s2v[8];
#pragma unroll
  for (int q = 0; q < 8; ++q) {
    const int d = q * 4 + hi;
    const float c = cen_g[kg * DIMN + d];
    const float s = std_g[kg * DIMN + d];
    cenv[q] = c; cen2v[q] = c * c; s2v[q] = s * s;
  }
  const float lw2 = __builtin_amdgcn_logf(w_g[kg]);   // log2(w_k)

  // ---- x init ----
  {
    const int b = tid >> 4, d0 = tid & 15;
    s_x[b][d0]      = xin[(size_t)(bbase + b) * DIMN + d0];
    s_x[b][d0 + 16] = xin[(size_t)(bbase + b) * DIMN + d0 + 16];
  }

  auto gen = [&](int jj) {
    const float tt = fmaf((float)(255 - jj) * (1.0f / 255.0f), TMAXc - TMINc, TMINc);
    const float Bt = fmaf(0.5f * (BMAX - BMIN), tt * tt, BMIN * tt);
    const float eB  = __builtin_amdgcn_exp2f(-Bt * L2E);
    const float om  = 1.0f - eB;
    const float smB = __builtin_amdgcn_sqrtf(eB);
    const float sL  = smB * L2E;           // a = cen * sL * (1/v)
    const float kq  = -0.5f * eB * L2E;    // -0.5*m^2*L2E/v = kq*cen^2/v
#pragma unroll
    for (int q = 0; q < 8; ++q) {
      const float v = fmaf(eB, s2v[q], om);
      const float r = __builtin_amdgcn_rcpf(v);
      const unsigned ivw = spack(L2E * r);
      const unsigned aw  = spack(cenv[q] * sL * r);
      const float lg = __builtin_amdgcn_logf(v);           // log2 v
      float g = fmaf(-16.0f, lg, kq * (cen2v[q] * r));
      if (q == 0) g += (hi == 0) ? lw2 : 0.0f;             // fold log2 w at d==0
      const unsigned gw = spack(g);
      s_pt[w][q][lane] = make_uint2(ivw, aw);
      const int d = q * 4 + hi;
      const int col = ((d >> 3) << 4) + ((d & 7) << 1);
      s_ot[col][kg]     = ivw;
      s_ot[col + 1][kg] = aw;
      ((unsigned*)&s_gt[w][q >> 2][((q & 3) << 4) + l15])[hi] = gw;
    }
  };

  auto dfrag = [&]() {   // data frags for P: [Hh,Hh | Hl,Hl | Xh,Xh | Xl,Xl]
#pragma unroll
    for (int s = 0; s < 2; ++s) {
      const int q = w + s * 4;
      const int d = q * 4 + hi;
      const float xv = s_x[l15][d];
      const float hv = -0.5f * xv * xv;
      const uint2 hs = bsplit(hv), xs = bsplit(xv);
      s_df[q][lane] = make_uint4(hs.x | (hs.x << 16), hs.y | (hs.y << 16),
                                 xs.x | (xs.x << 16), xs.y | (xs.y << 16));
    }
  };

  gen(0);
  __syncthreads();
  dfrag();
  __syncthreads();

  const bf16x8 ones = frag4(0x3F803F80u, 0x3F803F80u, 0x3F803F80u, 0x3F803F80u);
  const int dn = w * 8 + (l15 >> 1);     // this lane's d (O layout / update)
  const int su = l15 & 1;                // 0 = SIV col, 1 = SA col

#pragma unroll 1
  for (int j = 0; j < NST; ++j) {
    const float t  = fmaf((float)(255 - j) * (1.0f / 255.0f), TMAXc - TMINc, TMINc);
    const float tn = fmaf((float)(254 - j) * (1.0f / 255.0f), TMAXc - TMINc, TMINc);
    const float dt = tn - t;
    const float bt = fmaf(BMAX - BMIN, t, BMIN);
    const float cA  = fmaf(-0.5f * bt, dt, 1.0f);
    const float cb0 = (-bt * dt) * LN2;
    const float sq  = __builtin_amdgcn_sqrtf(bt) * __builtin_amdgcn_sqrtf(-dt);

    // noise prefetch (consumed at update)
    float z[4];
#pragma unroll
    for (int r = 0; r < 4; ++r)
      z[r] = noi[((size_t)j * BD + bbase + hi * 4 + r) * (size_t)DIMN + dn];

    // ---- P = data x tables (+ ones x G): D[b][k], this wave: k-tile w ----
    f32x4 acc = {0.0f, 0.0f, 0.0f, 0.0f};
#pragma unroll
    for (int q = 0; q < 8; ++q) {
      const uint4 df = s_df[q][lane];
      const uint2 pt = s_pt[w][q][lane];
      acc = __builtin_amdgcn_mfma_f32_16x16x32_bf16(
          frag4(df.x, df.y, df.z, df.w), frag4(pt.x, pt.x, pt.y, pt.y),
          acc, 0, 0, 0);
    }
#pragma unroll
    for (int g2 = 0; g2 < 2; ++g2) {
      const uint4 gt = s_gt[w][g2][lane];
      acc = __builtin_amdgcn_mfma_f32_16x16x32_bf16(
          ones, frag4(gt.x, gt.y, gt.z, gt.w), acc, 0, 0, 0);
    }

    // ---- softmax: lane holds (b = hi*4+r, k = w*16+l15) ----
    float mw[4];
#pragma unroll
    for (int r = 0; r < 4; ++r) mw[r] = bfly_max16(acc[r]);
    if (l15 == 0) {
#pragma unroll
      for (int r = 0; r < 4; ++r) s_pm[hi * 4 + r][w] = mw[r];
    }
    __syncthreads();   // S1: max partials

    float E[4];
#pragma unroll
    for (int r = 0; r < 4; ++r) {
      const float4 pm = *(const float4*)&s_pm[hi * 4 + r][0];
      const float M = fmaxf(fmaxf(pm.x, pm.y), fmaxf(pm.z, pm.w));
      E[r] = __builtin_amdgcn_exp2f(acc[r] - M);
    }
    float Lp[4];
#pragma unroll
    for (int r = 0; r < 4; ++r) Lp[r] = bfly_add16(E[r]);
    if (l15 == 0) {
#pragma unroll
      for (int r = 0; r < 4; ++r) s_pl[hi * 4 + r][w] = Lp[r];
    }
#pragma unroll
    for (int r = 0; r < 4; ++r)
      s_E[hi * 4 + r][w * 16 + l15] = spack(E[r]);
    __syncthreads();   // S2: E + L partials

    float cb2[4];
#pragma unroll
    for (int r = 0; r < 4; ++r) {
      const float4 pl = *(const float4*)&s_pl[hi * 4 + r][0];
      const float L = (pl.x + pl.y) + (pl.z + pl.w);
      cb2[r] = cb0 * __builtin_amdgcn_rcpf(L);
    }

    // ---- O = E x tables: D[b][col], this wave: cols w*16..w*16+15 ----
    f32x4 oc = {0.0f, 0.0f, 0.0f, 0.0f};
    const int colg = w * 16 + l15;
#pragma unroll
    for (int q = 0; q < 8; ++q) {
      const int k0 = q * 8 + hi * 2;
      const uint2 ev = *(const uint2*)&s_E[l15][k0];     // E(k0), E(k0+1)
      const uint2 tv = *(const uint2*)&s_ot[colg][k0];   // T(k0), T(k0+1)
      const unsigned lo0 = ev.x & 0xFFFFu, hi0 = ev.x >> 16;
      const unsigned lo1 = ev.y & 0xFFFFu, hi1 = ev.y >> 16;
      oc = __builtin_amdgcn_mfma_f32_16x16x32_bf16(
          frag4(lo0 | (lo0 << 16), hi0 | (hi0 << 16),
                lo1 | (lo1 << 16), hi1 | (hi1 << 16)),
          frag4(tv.x, tv.x, tv.y, tv.y), oc, 0, 0, 0);
    }

    // ---- Euler-Maruyama update: lane pair (SIV,SA) via DPP xor1 ----
#pragma unroll
    for (int r = 0; r < 4; ++r) {
      const int b = hi * 4 + r;
      const float xv = s_x[b][dn];
      const float pr = dpp_mov<0xB1>(oc[r]);
      const float siv = su ? pr : oc[r];
      const float sa  = su ? oc[r] : pr;
      const float xn = fmaf(cb2[r], fmaf(-xv, siv, sa),
                            fmaf(cA, xv, sq * z[r]));
      if (su == 0) {
        s_x[b][dn] = xn;
        if (j == NST - 1) out[(size_t)(bbase + b) * DIMN + dn] = xn;
      }
    }

    if (j + 1 < NST) {
      __syncthreads();   // B: x published; table reads of step j done
      gen(j + 1);
      dfrag();
      __syncthreads();   // C: tables + data frags ready
    }
  }
}

}  // namespace

extern "C" void kernel_launch(void* const* d_in, const int* in_sizes, int n_in,
                              void* d_out, int out_size, void* d_ws, size_t ws_size,
                              hipStream_t stream) {
  const float* x_init  = (const float*)d_in[0];
  const float* centers = (const float*)d_in[1];
  const float* stds    = (const float*)d_in[2];
  const float* weights = (const float*)d_in[3];
  const float* noise   = (const float*)d_in[4];
  float* out = (float*)d_out;

  sbm_kernel<<<dim3(512), dim3(256), 0, stream>>>(x_init, centers, stds, weights,
                                                  noise, out);
}